// Round 1
// baseline (703.624 us; speedup 1.0000x reference)
//
#include <hip/hip_runtime.h>
#include <math.h>

#define NS 16
#define NV 4
#define H  48
#define WN 320

__global__ __launch_bounds__(256) void edge_kernel(
    const float* __restrict__ node_attr,
    const float* __restrict__ edge_attr,
    const float* __restrict__ edge_vec,
    const float* __restrict__ fc1_w,
    const float* __restrict__ fc1_b,
    const float* __restrict__ fc2_w,
    const float* __restrict__ fc2_b,
    const int*   __restrict__ edge_index,
    float* __restrict__ out,
    float* __restrict__ cnt,
    int E)
{
    int e = blockIdx.x * blockDim.x + threadIdx.x;
    if (e >= E) return;

    float a[H];
    {
        const float4* p = reinterpret_cast<const float4*>(edge_attr + (size_t)e * H);
        #pragma unroll
        for (int i = 0; i < H/4; ++i) {
            float4 v = p[i];
            a[4*i+0] = v.x; a[4*i+1] = v.y; a[4*i+2] = v.z; a[4*i+3] = v.w;
        }
    }

    int dst = edge_index[E + e];
    float x[NS];
    {
        const float4* p = reinterpret_cast<const float4*>(node_attr + (size_t)dst * NS);
        #pragma unroll
        for (int i = 0; i < NS/4; ++i) {
            float4 v = p[i];
            x[4*i+0] = v.x; x[4*i+1] = v.y; x[4*i+2] = v.z; x[4*i+3] = v.w;
        }
    }

    float out0[NS];
    float o1[NV];
    #pragma unroll
    for (int w = 0; w < NS; ++w) out0[w] = 0.f;
    #pragma unroll
    for (int v = 0; v < NV; ++v) o1[v] = 0.f;

    #pragma unroll 1
    for (int k = 0; k < H; ++k) {
        float tk = fc1_b[k];
        #pragma unroll
        for (int j = 0; j < H; ++j)
            tk = fmaf(a[j], fc1_w[j*H + k], tk);
        tk = fmaxf(tk, 0.f);

        const float* __restrict__ row = fc2_w + k*WN;
        #pragma unroll
        for (int u = 0; u < NS; ++u) {
            float q = tk * x[u];
            #pragma unroll
            for (int w = 0; w < NS; ++w)
                out0[w] = fmaf(q, row[u*NS + w], out0[w]);
            #pragma unroll
            for (int v = 0; v < NV; ++v)
                o1[v] = fmaf(q, row[NS*NS + u*NV + v], o1[v]);
        }
    }

    #pragma unroll
    for (int u = 0; u < NS; ++u) {
        float xu = x[u];
        #pragma unroll
        for (int w = 0; w < NS; ++w)
            out0[w] = fmaf(xu, fc2_b[u*NS + w], out0[w]);
        #pragma unroll
        for (int v = 0; v < NV; ++v)
            o1[v] = fmaf(xu, fc2_b[NS*NS + u*NV + v], o1[v]);
    }

    float vx = edge_vec[3*(size_t)e + 0];
    float vy = edge_vec[3*(size_t)e + 1];
    float vz = edge_vec[3*(size_t)e + 2];
    float rn = 1.0f / (sqrtf(vx*vx + vy*vy + vz*vz) + 1e-8f);
    const float c1 = 1.7320508075688772f;
    float s1x = c1 * vx * rn, s1y = c1 * vy * rn, s1z = c1 * vz * rn;

    const float inv = 0.25f;
    int src = edge_index[e];
    float* ob = out + (size_t)src * 28;

    #pragma unroll
    for (int w = 0; w < NS; ++w)
        atomicAdd(ob + w, out0[w] * inv);
    #pragma unroll
    for (int v = 0; v < NV; ++v) {
        float q = o1[v] * inv;
        atomicAdd(ob + NS + 3*v + 0, q * s1x);
        atomicAdd(ob + NS + 3*v + 1, q * s1y);
        atomicAdd(ob + NS + 3*v + 2, q * s1z);
    }
    atomicAdd(cnt + src, 1.0f);
}

__global__ __launch_bounds__(256) void finalize_kernel(
    float* __restrict__ out, const float* __restrict__ cnt, int total)
{
    int i = blockIdx.x * blockDim.x + threadIdx.x;
    if (i < total) {
        float c = cnt[i / 28];
        out[i] = out[i] / fmaxf(c, 1.0f);
    }
}

extern "C" void kernel_launch(void* const* d_in, const int* in_sizes, int n_in,
                              void* d_out, int out_size, void* d_ws, size_t ws_size,
                              hipStream_t stream) {
    const float* node_attr = (const float*)d_in[0];
    const float* edge_attr = (const float*)d_in[1];
    const float* edge_vec  = (const float*)d_in[2];
    const float* fc1_w     = (const float*)d_in[3];
    const float* fc1_b     = (const float*)d_in[4];
    const float* fc2_w     = (const float*)d_in[5];
    const float* fc2_b     = (const float*)d_in[6];
    const int*   edge_index= (const int*)d_in[7];

    int E = in_sizes[2] / 3;
    int N = in_sizes[0] / NS;
    float* out = (float*)d_out;
    float* cnt = (float*)d_ws;

    hipMemsetAsync(d_out, 0, (size_t)out_size * sizeof(float), stream);
    hipMemsetAsync(d_ws, 0, (size_t)N * sizeof(float), stream);

    edge_kernel<<<(E + 255)/256, 256, 0, stream>>>(
        node_attr, edge_attr, edge_vec, fc1_w, fc1_b, fc2_w, fc2_b,
        edge_index, out, cnt, E);

    int total = N * 28;
    finalize_kernel<<<(total + 255)/256, 256, 0, stream>>>(out, cnt, total);
}

// Round 2
// 227.008 us; speedup vs baseline: 3.0996x; 3.0996x over previous
//
#include <hip/hip_runtime.h>
#include <hip/hip_bf16.h>
#include <math.h>

#define NS 16
#define NV 4
#define H  48
#define TM 64            // edges per tile
#define NBLK 512         // persistent blocks (2/CU resident)

typedef __attribute__((ext_vector_type(8))) short bf16x8;
typedef __attribute__((ext_vector_type(4))) float f32x4;

// LDS tiles are [rows][64] bf16 (row stride 128 B). Swizzle: XOR the 16B slot
// by row&7 (T2 st-style) so stride-128B column reads are conflict-free.
// Index space is halfwords (shorts).
__device__ __forceinline__ int swz(int row, int col) {
    return ((row << 6) + col) ^ ((row & 7) << 3);
}

#define A_OFF  0        // sA  [64][64]
#define T_OFF  4096     // sT  [64][64]
#define W1_OFF 8192     // fc1^T [48][64]
#define W2_OFF 11264    // fc2^T [320][64]
#define SMEM_HW 31744   // 63488 bytes

__device__ __forceinline__ short f2bf(float f) {
    unsigned b = __float_as_uint(f);
    unsigned r = (b + 0x7FFFu + ((b >> 16) & 1u)) >> 16;
    return (short)r;
}

__global__ __launch_bounds__(256, 2) void edge_mfma_kernel(
    const float* __restrict__ node_attr,
    const float* __restrict__ edge_attr,
    const float* __restrict__ edge_vec,
    const float* __restrict__ fc1_w,
    const float* __restrict__ fc1_b,
    const float* __restrict__ fc2_w,
    const float* __restrict__ fc2_b,
    const int*   __restrict__ edge_index,
    float* __restrict__ out,
    float* __restrict__ cnt,
    int E, int ntiles)
{
    __shared__ __align__(16) short smem[SMEM_HW];
    const int tid = threadIdx.x;

    // ---- one-time weight staging (bf16, transposed, swizzled) ----
    // fc1_w[j][n] -> W1T[n][j]
    for (int idx = tid; idx < 48 * 48; idx += 256) {
        int j = idx / 48, n = idx % 48;
        smem[W1_OFF + swz(n, j)] = f2bf(fc1_w[idx]);
    }
    // bias row (col 48) + zero pad cols 49..63
    for (int idx = tid; idx < 48 * 16; idx += 256) {
        int n = idx / 16, jj = idx % 16;
        smem[W1_OFF + swz(n, 48 + jj)] = (jj == 0) ? f2bf(fc1_b[n]) : (short)0;
    }
    // fc2_w[j][n] -> W2T[n][j]
    for (int idx = tid; idx < 48 * 320; idx += 256) {
        int j = idx / 320, n = idx % 320;
        smem[W2_OFF + swz(n, j)] = f2bf(fc2_w[idx]);
    }
    for (int idx = tid; idx < 320 * 16; idx += 256) {
        int n = idx / 16, jj = idx % 16;
        smem[W2_OFF + swz(n, 48 + jj)] = (jj == 0) ? f2bf(fc2_b[n]) : (short)0;
    }
    // sA / sT constant high columns: col 48 = 1.0 (bias multiplier), 49..63 = 0
    for (int idx = tid; idx < 64 * 16; idx += 256) {
        int r = idx / 16, jj = idx % 16;
        short v = (jj == 0) ? (short)0x3F80 : (short)0;
        smem[A_OFF + swz(r, 48 + jj)] = v;
        smem[T_OFF + swz(r, 48 + jj)] = v;
    }
    __syncthreads();
    // After this point there is NO cross-wave LDS sharing of mutable data:
    // wave wv stages/reads only sA/sT rows [wv*16, wv*16+16). No more barriers.

    const int l  = tid & 63;
    const int wv = tid >> 6;   // wave 0..3
    const int g  = l >> 4;     // 16-lane group 0..3
    const int c  = l & 15;     // col / lane-in-group

    for (int tile = blockIdx.x; tile < ntiles; tile += NBLK) {
        const int base = tile * TM;

        // ---- stage sA: rows wv*16..wv*16+15 are written by this wave's tids ----
        {
            int r = tid >> 2;          // 0..63  (wave wv covers rows 16wv..16wv+15)
            int q = tid & 3;           // quarter: 12 cols each
            int e = base + r;
            float4 v0, v1, v2;
            if (e < E) {
                const float* src = edge_attr + (size_t)e * H + q * 12;
                v0 = *(const float4*)(src + 0);
                v1 = *(const float4*)(src + 4);
                v2 = *(const float4*)(src + 8);
            } else {
                v0 = make_float4(0.f, 0.f, 0.f, 0.f); v1 = v0; v2 = v0;
            }
            short4 s0 = make_short4(f2bf(v0.x), f2bf(v0.y), f2bf(v0.z), f2bf(v0.w));
            short4 s1 = make_short4(f2bf(v1.x), f2bf(v1.y), f2bf(v1.z), f2bf(v1.w));
            short4 s2v = make_short4(f2bf(v2.x), f2bf(v2.y), f2bf(v2.z), f2bf(v2.w));
            *(short4*)&smem[A_OFF + swz(r, q * 12 + 0)] = s0;
            *(short4*)&smem[A_OFF + swz(r, q * 12 + 4)] = s1;
            *(short4*)&smem[A_OFF + swz(r, q * 12 + 8)] = s2v;
        }

        // ---- per-lane gathers (issued early; consumed in GEMM2 contraction) ----
        const int e0 = base + wv * 16 + g * 4;  // + j
        int srcj[4];
        float xr[4][16];
        float shx[4], shy[4], shz[4];
        #pragma unroll
        for (int j = 0; j < 4; ++j) {
            int e = e0 + j;
            int ce = (e < E) ? e : 0;
            int dst = edge_index[E + ce];
            srcj[j] = edge_index[ce];
            const float* xp = node_attr + (size_t)dst * NS;
            #pragma unroll
            for (int u4 = 0; u4 < 4; ++u4) {
                float4 t = *(const float4*)(xp + u4 * 4);
                xr[j][u4 * 4 + 0] = t.x; xr[j][u4 * 4 + 1] = t.y;
                xr[j][u4 * 4 + 2] = t.z; xr[j][u4 * 4 + 3] = t.w;
            }
            float vx = edge_vec[3 * (size_t)ce + 0];
            float vy = edge_vec[3 * (size_t)ce + 1];
            float vz = edge_vec[3 * (size_t)ce + 2];
            float rn = 1.0f / (sqrtf(vx * vx + vy * vy + vz * vz) + 1e-8f);
            const float c1 = 1.7320508075688772f;
            shx[j] = c1 * vx * rn; shy[j] = c1 * vy * rn; shz[j] = c1 * vz * rn;
        }

        // ---- GEMM1: t[16,48] = relu(A[16,64] x W1T^T) for this wave's rows ----
        const int rowA = wv * 16 + c;
        bf16x8 a0 = *(const bf16x8*)&smem[A_OFF + swz(rowA, g * 8)];
        bf16x8 a1 = *(const bf16x8*)&smem[A_OFF + swz(rowA, g * 8 + 32)];
        #pragma unroll
        for (int fr = 0; fr < 3; ++fr) {
            f32x4 acc = {0.f, 0.f, 0.f, 0.f};
            bf16x8 b0 = *(const bf16x8*)&smem[W1_OFF + swz(fr * 16 + c, g * 8)];
            bf16x8 b1 = *(const bf16x8*)&smem[W1_OFF + swz(fr * 16 + c, g * 8 + 32)];
            acc = __builtin_amdgcn_mfma_f32_16x16x32_bf16(a0, b0, acc, 0, 0, 0);
            acc = __builtin_amdgcn_mfma_f32_16x16x32_bf16(a1, b1, acc, 0, 0, 0);
            // relu -> bf16 -> sT (C layout: row=(g*4+j), col=fr*16+c, own wave rows)
            #pragma unroll
            for (int j = 0; j < 4; ++j) {
                smem[T_OFF + swz(wv * 16 + g * 4 + j, fr * 16 + c)] =
                    f2bf(fmaxf(acc[j], 0.f));
            }
        }

        // ---- GEMM2 + fused contraction with x ----
        bf16x8 t0 = *(const bf16x8*)&smem[T_OFF + swz(rowA, g * 8)];
        bf16x8 t1 = *(const bf16x8*)&smem[T_OFF + swz(rowA, g * 8 + 32)];

        float o0[4] = {0.f, 0.f, 0.f, 0.f};
        #pragma unroll
        for (int u = 0; u < 16; ++u) {   // w0 fragments: cols u*16..u*16+15
            f32x4 acc = {0.f, 0.f, 0.f, 0.f};
            bf16x8 b0 = *(const bf16x8*)&smem[W2_OFF + swz(u * 16 + c, g * 8)];
            bf16x8 b1 = *(const bf16x8*)&smem[W2_OFF + swz(u * 16 + c, g * 8 + 32)];
            acc = __builtin_amdgcn_mfma_f32_16x16x32_bf16(t0, b0, acc, 0, 0, 0);
            acc = __builtin_amdgcn_mfma_f32_16x16x32_bf16(t1, b1, acc, 0, 0, 0);
            #pragma unroll
            for (int j = 0; j < 4; ++j)
                o0[j] = fmaf(xr[j][u], acc[j], o0[j]);
        }

        float o1[4] = {0.f, 0.f, 0.f, 0.f};
        const int s2 = c >> 2;
        #pragma unroll
        for (int f = 0; f < 4; ++f) {    // w1 fragments: cols 256+f*16..+15
            f32x4 acc = {0.f, 0.f, 0.f, 0.f};
            bf16x8 b0 = *(const bf16x8*)&smem[W2_OFF + swz(256 + f * 16 + c, g * 8)];
            bf16x8 b1 = *(const bf16x8*)&smem[W2_OFF + swz(256 + f * 16 + c, g * 8 + 32)];
            acc = __builtin_amdgcn_mfma_f32_16x16x32_bf16(t0, b0, acc, 0, 0, 0);
            acc = __builtin_amdgcn_mfma_f32_16x16x32_bf16(t1, b1, acc, 0, 0, 0);
            // lane's col = u*4+v with u = f*4 + (c>>2), v = c&3
            #pragma unroll
            for (int j = 0; j < 4; ++j) {
                float xv = xr[j][f * 4 + 0];
                xv = (s2 == 1) ? xr[j][f * 4 + 1] : xv;
                xv = (s2 == 2) ? xr[j][f * 4 + 2] : xv;
                xv = (s2 == 3) ? xr[j][f * 4 + 3] : xv;
                o1[j] = fmaf(xv, acc[j], o1[j]);
            }
        }
        // sum the 4 u-partials (lanes c, c+4, c+8, c+12 share v=c&3)
        #pragma unroll
        for (int j = 0; j < 4; ++j) {
            o1[j] += __shfl_xor(o1[j], 4);
            o1[j] += __shfl_xor(o1[j], 8);
        }

        // ---- epilogue: scaled atomics into out / cnt ----
        const float inv = 0.25f;  // 1/sqrt(NS)
        #pragma unroll
        for (int j = 0; j < 4; ++j) {
            int e = e0 + j;
            if (e < E) {
                float* ob = out + (size_t)srcj[j] * 28;
                atomicAdd(ob + c, o0[j] * inv);
                if (c < 4) {
                    float q = o1[j] * inv;
                    atomicAdd(ob + 16 + 3 * c + 0, q * shx[j]);
                    atomicAdd(ob + 16 + 3 * c + 1, q * shy[j]);
                    atomicAdd(ob + 16 + 3 * c + 2, q * shz[j]);
                }
                if (c == 0) atomicAdd(cnt + srcj[j], 1.0f);
            }
        }
    }
}

__global__ __launch_bounds__(256) void finalize_kernel(
    float* __restrict__ out, const float* __restrict__ cnt, int total)
{
    int i = blockIdx.x * blockDim.x + threadIdx.x;
    if (i < total) {
        float cv = cnt[i / 28];
        out[i] = out[i] / fmaxf(cv, 1.0f);
    }
}

extern "C" void kernel_launch(void* const* d_in, const int* in_sizes, int n_in,
                              void* d_out, int out_size, void* d_ws, size_t ws_size,
                              hipStream_t stream) {
    const float* node_attr  = (const float*)d_in[0];
    const float* edge_attr  = (const float*)d_in[1];
    const float* edge_vec   = (const float*)d_in[2];
    const float* fc1_w      = (const float*)d_in[3];
    const float* fc1_b      = (const float*)d_in[4];
    const float* fc2_w      = (const float*)d_in[5];
    const float* fc2_b      = (const float*)d_in[6];
    const int*   edge_index = (const int*)d_in[7];

    int E = in_sizes[2] / 3;      // 400000
    int N = in_sizes[0] / NS;     // 50000
    float* out = (float*)d_out;
    float* cnt = (float*)d_ws;

    hipMemsetAsync(d_out, 0, (size_t)out_size * sizeof(float), stream);
    hipMemsetAsync(d_ws, 0, (size_t)N * sizeof(float), stream);

    int ntiles = (E + TM - 1) / TM;
    edge_mfma_kernel<<<NBLK, 256, 0, stream>>>(
        node_attr, edge_attr, edge_vec, fc1_w, fc1_b, fc2_w, fc2_b,
        edge_index, out, cnt, E, ntiles);

    int total = N * 28;
    finalize_kernel<<<(total + 255) / 256, 256, 0, stream>>>(out, cnt, total);
}